// Round 14
// baseline (116.188 us; speedup 1.0000x reference)
//
#include <hip/hip_runtime.h>
#include <hip/hip_bf16.h>

// Problem constants (fixed by setup_inputs)
#define BB 2
#define LL 4096
#define HH 32
#define DV 64
#define DQK 128
#define CC 64            // chunk size
#define NN 64            // number of chunks = LL/CC
#define MIMO_RANK 4.0f

typedef __attribute__((ext_vector_type(8))) short short8;
typedef __attribute__((ext_vector_type(4))) float f32x4;

__device__ __forceinline__ ushort f2bf(float f) {
    __hip_bfloat16 h = __float2bfloat16(f);   // RNE; compiler emits HW cvt
    return *reinterpret_cast<ushort*>(&h);
}
__device__ __forceinline__ float bfbits2f(uint lo16) {
    return __uint_as_float(lo16 << 16);
}
__device__ __forceinline__ uint pkbf2(float lo, float hi) {
    return (uint)f2bf(lo) | ((uint)f2bf(hi) << 16);
}
union U8 { uint u[4]; short8 s; };

// ---- LDS swizzled-offset helpers (element offsets in ushorts) ----
// rk: [64 s][128 d], 16 slots/row, slot ^= (s&7)
__device__ __forceinline__ int rk_off(int s, int d) {
    return s * 128 + (((((d >> 3) & 15) ^ (s & 7)) << 3)) + (d & 7);
}
// uwT: [64 e][64 s], slot ^= (e&7)
__device__ __forceinline__ int uwT_off(int e, int s) {
    return e * 64 + ((((s >> 3) ^ (e & 7)) & 7) << 3) + (s & 7);
}
// SL: [64 t][64 s], slot ^= fSL(t)
__device__ __forceinline__ int fSL(int t) {
    return (((t & 3) << 1) ^ ((t >> 2) & 7)) & 7;
}
__device__ __forceinline__ int SL_off(int t, int s) {
    return t * 64 + ((((s >> 3) ^ fSL(t)) & 7) << 3) + (s & 7);
}

// Build the 4 A-fragments (K=128) of a rotary-transformed row in registers.
__device__ __forceinline__ void make_rot_frags(const float* __restrict__ G,
                                               size_t gb, float cv, float sv,
                                               int kgrp, short8* fr) {
    #pragma unroll
    for (int kk = 0; kk < 4; ++kk) {
        int d0 = kk * 32 + kgrp;
        int dl = d0 & 63;
        bool low = d0 < 64;
        float4 a1 = *(const float4*)(G + gb + dl);
        float4 b1 = *(const float4*)(G + gb + dl + 4);
        float4 a2 = *(const float4*)(G + gb + dl + 64);
        float4 b2 = *(const float4*)(G + gb + dl + 68);
        float v0, v1, v2, v3, v4, v5, v6, v7;
        if (low) {
            v0 = a1.x * cv - a2.x * sv; v1 = a1.y * cv - a2.y * sv;
            v2 = a1.z * cv - a2.z * sv; v3 = a1.w * cv - a2.w * sv;
            v4 = b1.x * cv - b2.x * sv; v5 = b1.y * cv - b2.y * sv;
            v6 = b1.z * cv - b2.z * sv; v7 = b1.w * cv - b2.w * sv;
        } else {
            v0 = a1.x * sv + a2.x * cv; v1 = a1.y * sv + a2.y * cv;
            v2 = a1.z * sv + a2.z * cv; v3 = a1.w * sv + a2.w * cv;
            v4 = b1.x * sv + b2.x * cv; v5 = b1.y * sv + b2.y * cv;
            v6 = b1.z * sv + b2.z * cv; v7 = b1.w * sv + b2.w * cv;
        }
        U8 r;
        r.u[0] = pkbf2(v0, v1); r.u[1] = pkbf2(v2, v3);
        r.u[2] = pkbf2(v4, v5); r.u[3] = pkbf2(v6, v7);
        fr[kk] = r.s;
    }
}

// ---------------------------------------------------------------------------
// K1: prefix sum of dt per (b,h) + precompute table (cos, sin, dt*dw, et)
// per t, plus cdecay per chunk. tbl layout: float4 [b][h][l].
// ---------------------------------------------------------------------------
__global__ __launch_bounds__(256) void k_scan_dt(const float* __restrict__ dt,
                                                 const float* __restrict__ A,
                                                 float4* __restrict__ tbl,
                                                 float* __restrict__ cdecay) {
    int bh = blockIdx.x;
    int b = bh / HH, h = bh % HH;
    int tid = threadIdx.x;
    const int PT = LL / 256;  // 16
    float v[PT];
    float s = 0.f;
    int tbase = tid * PT;
    for (int i = 0; i < PT; ++i) {
        v[i] = dt[(((size_t)b * LL + tbase + i) * HH) + h];
        s += v[i];
    }
    int lane = tid & 63, wv = tid >> 6;
    float ps = s;
    for (int off = 1; off < 64; off <<= 1) {
        float o = __shfl_up(ps, off, 64);
        if (lane >= off) ps += o;
    }
    __shared__ float wsum[4];
    if (lane == 63) wsum[wv] = ps;
    __syncthreads();
    float wadd = 0.f;
    for (int w = 0; w < wv; ++w) wadd += wsum[w];
    float run0 = wadd + ps - s;        // exclusive prefix at tbase
    float run_end = run0 + s;          // inclusive at tbase+15
    float aend  = __shfl(run_end, lane | 3, 64);   // inclusive at chunk end
    float aprev = __shfl(run0, lane & ~3, 64);     // exclusive at chunk start
    float Ah = A[h];
    if ((tid & 3) == 0) {
        int n = tid >> 2;
        cdecay[(b * NN + n) * HH + h] = __expf(Ah * (aend - aprev));
    }
    float4* tb = tbl + ((size_t)(b * HH + h) * LL) + tbase;
    float run = run0;
    for (int i = 0; i < PT; ++i) {
        run += v[i];
        float sv, cv;
        __sincosf(run, &sv, &cv);
        float dw = __expf(Ah * (aend - run));   // decay to chunk end (<=1)
        float et = __expf(Ah * (run - aend));   // inverse factor (>=1)
        tb[i] = make_float4(cv, sv, v[i] * dw, et);
    }
}

// ---------------------------------------------------------------------------
// K2: per-(b,n,h) intra-chunk tile. LDS = 41984 B -> 3 blocks/CU.
// global_load_lds staging (round-13-proven). Epilogue now stores bf16 ytmp
// (= 4*y_intra + D*x) instead of f32 out — k_inter finalizes.
// ---------------------------------------------------------------------------
__global__ __launch_bounds__(256, 3) void k_intra(
    const float* __restrict__ x, const float* __restrict__ Bg,
    const float* __restrict__ Cg, const float4* __restrict__ tbl,
    const float* __restrict__ Dd,
    ushort* __restrict__ ytmp, ushort* __restrict__ dH) {
    int n = blockIdx.x, h = blockIdx.y, b = blockIdx.z;
    int tid = threadIdx.x;
    int t0 = n * CC;

    __shared__ ushort rkS[CC * DQK];     // 16384 B; first 8192 B alias SL later
    __shared__ ushort uwT[DV * CC];      // 8192 B
    __shared__ float4 tblLds[CC];        // 1024 B
    __shared__ float  xraw[CC * DV];     // 16384 B  (row-major [s][e])
    // total 41984 B -> 3 blocks/CU

    int wv = tid >> 6, lane = tid & 63;
    int lrow = lane & 15;
    int g = lane >> 4;
    int kgrp = g * 8;
    int orow = g * 4;

    const float* BgRow = Bg + ((size_t)b * LL + t0) * DQK;  // row s stride 128

    // ============ STEP 0: issue ALL loads (async LDS + reg) ============
    {
        const float4* tbsrc = tbl + ((size_t)(b * HH + h) * LL) + t0 + lane;
        __builtin_amdgcn_global_load_lds((const void*)tbsrc, (void*)tblLds,
                                         16, 0, 0);
    }
    #pragma unroll
    for (int i = 0; i < 4; ++i) {
        int row = 16 * wv + 4 * i + (lane >> 4);
        const float* xsrc = x + ((((size_t)b * LL + t0 + row) * HH) + h) * DV
                            + 4 * (lane & 15);
        __builtin_amdgcn_global_load_lds((const void*)xsrc,
                                         (void*)(xraw + (16 * wv + 4 * i) * DV),
                                         16, 0, 0);
    }
    float4 bg0[2], bg1[2], bg2[2], bg3[2];
    #pragma unroll
    for (int it = 0; it < 2; ++it) {
        int s = (tid >> 3) + 32 * it, oct = tid & 7;
        const float* p = BgRow + s * DQK + 8 * oct;
        bg0[it] = *(const float4*)(p);
        bg1[it] = *(const float4*)(p + 4);
        bg2[it] = *(const float4*)(p + 64);
        bg3[it] = *(const float4*)(p + 68);
    }

    asm volatile("s_waitcnt vmcnt(0)" ::: "memory");
    __builtin_amdgcn_sched_barrier(0);

    // ============ STEP 1: rq frags (Cg loads issue under packing) ============
    int t_own = 16 * wv + lrow;
    float4 tq = tblLds[t_own];
    short8 aq[4];
    make_rot_frags(Cg, ((size_t)b * LL + t0 + t_own) * DQK, tq.x, tq.y, kgrp, aq);

    // ============ STEP 2: rkS pack + write (trig from tblLds) ============
    #pragma unroll
    for (int it = 0; it < 2; ++it) {
        int s = (tid >> 3) + 32 * it, oct = tid & 7;
        float4 tv = tblLds[s];
        float cv = tv.x, sv = tv.y;
        U8 lo, hi;
        lo.u[0] = pkbf2(bg0[it].x * cv - bg2[it].x * sv, bg0[it].y * cv - bg2[it].y * sv);
        lo.u[1] = pkbf2(bg0[it].z * cv - bg2[it].z * sv, bg0[it].w * cv - bg2[it].w * sv);
        lo.u[2] = pkbf2(bg1[it].x * cv - bg3[it].x * sv, bg1[it].y * cv - bg3[it].y * sv);
        lo.u[3] = pkbf2(bg1[it].z * cv - bg3[it].z * sv, bg1[it].w * cv - bg3[it].w * sv);
        hi.u[0] = pkbf2(bg0[it].x * sv + bg2[it].x * cv, bg0[it].y * sv + bg2[it].y * cv);
        hi.u[1] = pkbf2(bg0[it].z * sv + bg2[it].z * cv, bg0[it].w * sv + bg2[it].w * cv);
        hi.u[2] = pkbf2(bg1[it].x * sv + bg3[it].x * cv, bg1[it].y * sv + bg3[it].y * cv);
        hi.u[3] = pkbf2(bg1[it].z * sv + bg3[it].z * cv, bg1[it].w * sv + bg3[it].w * cv);
        *(short8*)&rkS[rk_off(s, 8 * oct)] = lo.s;
        *(short8*)&rkS[rk_off(s, 8 * oct + 64)] = hi.s;
    }

    // ============ STEP 3: uwT from xraw (own-wave rows only) ============
    #pragma unroll
    for (int it = 0; it < 2; ++it) {
        int s0 = 16 * wv + 8 * it;       // within this wave's xraw rows
        int e = lane;
        U8 pk;
        #pragma unroll
        for (int jp = 0; jp < 4; ++jp) {
            int sa = s0 + 2 * jp, sb = sa + 1;
            float xa = xraw[sa * DV + e] * tblLds[sa].z;
            float xb = xraw[sb * DV + e] * tblLds[sb].z;
            pk.u[jp] = pkbf2(xa, xb);
        }
        *(short8*)&uwT[uwT_off(e, s0)] = pk.s;
    }

    __syncthreads();  // BARRIER A: rkS + uwT staged

    // ---- Phase 1: S = rq . rk^T (m = t-rows of wave, n = s, K = 128) ----
    f32x4 accS[4] = {{0.f,0.f,0.f,0.f},{0.f,0.f,0.f,0.f},
                     {0.f,0.f,0.f,0.f},{0.f,0.f,0.f,0.f}};
    #pragma unroll
    for (int kk = 0; kk < 4; ++kk) {
        #pragma unroll
        for (int nt = 0; nt < 4; ++nt) {
            int s = 16 * nt + lrow;
            const short8 bfr = *(const short8*)&rkS[rk_off(s, 32 * kk + kgrp)];
            accS[nt] = __builtin_amdgcn_mfma_f32_16x16x32_bf16(
                aq[kk], bfr, accS[nt], 0, 0, 0);
        }
    }

    // ---- build phase-3 A-frags in registers: aH[kk][mt] = rk[s][d] slices ----
    short8 aH[2][2];
    #pragma unroll
    for (int kk = 0; kk < 2; ++kk) {
        #pragma unroll
        for (int mt = 0; mt < 2; ++mt) {
            int d = 32 * wv + 16 * mt + lrow;
            uint vv[8];
            #pragma unroll
            for (int j = 0; j < 8; ++j)
                vv[j] = rkS[rk_off(32 * kk + kgrp + j, d)];
            U8 pk;
            pk.u[0] = vv[0] | (vv[1] << 16);
            pk.u[1] = vv[2] | (vv[3] << 16);
            pk.u[2] = vv[4] | (vv[5] << 16);
            pk.u[3] = vv[6] | (vv[7] << 16);
            aH[kk][mt] = pk.s;
        }
    }

    __syncthreads();  // BARRIER B: all rkS reads complete -> alias as SL

    // ---- SL = mask(t>=s) * S * et[t], into rkS alias ----
    ushort* SLs = rkS;
    #pragma unroll
    for (int rr = 0; rr < 4; ++rr) {
        int t = 16 * wv + orow + rr;
        float etv = tblLds[t].w;
        #pragma unroll
        for (int nt = 0; nt < 4; ++nt) {
            int s = 16 * nt + lrow;
            float v = (t >= s) ? accS[nt][rr] * etv : 0.f;
            SLs[SL_off(t, s)] = f2bf(v);
        }
    }

    __syncthreads();  // BARRIER C: SL visible

    // ---- Phase 2: y_intra = SL . uwT^T ; ytmp = bf16(4*y + D*x) ----
    {
        f32x4 accY[4] = {{0.f,0.f,0.f,0.f},{0.f,0.f,0.f,0.f},
                         {0.f,0.f,0.f,0.f},{0.f,0.f,0.f,0.f}};
        #pragma unroll
        for (int kk = 0; kk < 2; ++kk) {
            const short8 a = *(const short8*)&SLs[SL_off(16 * wv + lrow, 32 * kk + kgrp)];
            #pragma unroll
            for (int nt = 0; nt < 4; ++nt) {
                const short8 bfr = *(const short8*)&uwT[uwT_off(16 * nt + lrow, 32 * kk + kgrp)];
                accY[nt] = __builtin_amdgcn_mfma_f32_16x16x32_bf16(
                    a, bfr, accY[nt], 0, 0, 0);
            }
        }
        float Dh = Dd[h];
        #pragma unroll
        for (int nt = 0; nt < 4; ++nt) {
            int e = 16 * nt + lrow;
            #pragma unroll
            for (int rr = 0; rr < 4; ++rr) {
                int t = 16 * wv + orow + rr;    // within this wave's xraw rows
                size_t oidx = ((((size_t)b * LL + t0 + t) * HH) + h) * DV + e;
                ytmp[oidx] = f2bf(MIMO_RANK * accY[nt][rr] + Dh * xraw[t * DV + e]);
            }
        }
    }

    // ---- Phase 3: dH = rk^T . uwT^T (m = d, n = e, K = 64), A from regs ----
    {
        f32x4 accH[2][4] = {{{0.f,0.f,0.f,0.f},{0.f,0.f,0.f,0.f},
                             {0.f,0.f,0.f,0.f},{0.f,0.f,0.f,0.f}},
                            {{0.f,0.f,0.f,0.f},{0.f,0.f,0.f,0.f},
                             {0.f,0.f,0.f,0.f},{0.f,0.f,0.f,0.f}}};
        #pragma unroll
        for (int kk = 0; kk < 2; ++kk) {
            #pragma unroll
            for (int mt = 0; mt < 2; ++mt) {
                #pragma unroll
                for (int nt = 0; nt < 4; ++nt) {
                    const short8 bfr = *(const short8*)&uwT[uwT_off(16 * nt + lrow, 32 * kk + kgrp)];
                    accH[mt][nt] = __builtin_amdgcn_mfma_f32_16x16x32_bf16(
                        aH[kk][mt], bfr, accH[mt][nt], 0, 0, 0);
                }
            }
        }
        ushort* dHp = dH + (((size_t)(b * NN + n) * HH) + h) * (DQK * DV);
        #pragma unroll
        for (int q = 0; q < 4; ++q) {
            int mt = q >> 1, np = q & 1;
            U8 st;
            st.u[0] = pkbf2(accH[mt][2 * np][0], accH[mt][2 * np][1]);
            st.u[1] = pkbf2(accH[mt][2 * np][2], accH[mt][2 * np][3]);
            st.u[2] = pkbf2(accH[mt][2 * np + 1][0], accH[mt][2 * np + 1][1]);
            st.u[3] = pkbf2(accH[mt][2 * np + 1][2], accH[mt][2 * np + 1][3]);
            *(short8*)(dHp + ((size_t)(wv * 4 + q) * 64 + lane) * 8) = st.s;
        }
    }
}

// ---------------------------------------------------------------------------
// K3: sequential chunk scan, in place, uint2 (4 bf16 lanes) per thread.
// Per-(b,n) plane = 2^16 uint2; thread owns (b,h,pos) and loops n.
// ---------------------------------------------------------------------------
__global__ __launch_bounds__(256) void k_scan_chunks(
    uint2* __restrict__ dH, const float* __restrict__ cdecay) {
    uint f = blockIdx.x * 256 + threadIdx.x;   // 0..131071
    int b = (int)(f >> 16);
    uint pos = f & 0xFFFF;
    int h = (int)((pos >> 11) & 31);
    uint base = ((uint)b << 22) + pos;
    const float* cd = cdecay + (size_t)b * NN * HH + h;
    float h0 = 0.f, h1 = 0.f, h2 = 0.f, h3 = 0.f;
    for (int n = 0; n < NN; ++n) {
        uint a = base + ((uint)n << 16);
        uint2 v = dH[a];
        float v0 = bfbits2f(v.x & 0xFFFF), v1 = bfbits2f(v.x >> 16);
        float v2 = bfbits2f(v.y & 0xFFFF), v3 = bfbits2f(v.y >> 16);
        uint2 st;
        st.x = pkbf2(h0, h1);
        st.y = pkbf2(h2, h3);
        dH[a] = st;                    // Hprev for chunk n
        float c = cd[n * HH];
        h0 = c * h0 + v0; h1 = c * h1 + v1;
        h2 = c * h2 + v2; h3 = c * h3 + v3;
    }
}

// ---------------------------------------------------------------------------
// K4: y_inter + final combine. out = ytmp + 4*et[t]*cdecay[n]*y_inter.
// Single f32 out write (no RMW read of out).
// ---------------------------------------------------------------------------
__global__ __launch_bounds__(256, 6) void k_inter(
    const float* __restrict__ Cg, const float4* __restrict__ tbl,
    const float* __restrict__ cdecay, const ushort* __restrict__ Hprev,
    const ushort* __restrict__ ytmp, float* __restrict__ out) {
    int n = blockIdx.x, h = blockIdx.y, b = blockIdx.z;
    int tid = threadIdx.x;
    int t0 = n * CC;

    __shared__ __align__(16) uint Hp[16 * 260];  // rows 16B-aligned

    const float4* tb = tbl + ((size_t)(b * HH + h) * LL) + t0;
    float cdec = cdecay[(b * NN + n) * HH + h];

    const uint* Hsrc = (const uint*)(Hprev + (((size_t)(b * NN + n) * HH) + h) * (DQK * DV));
    #pragma unroll
    for (int it = 0; it < 4; ++it) {
        int p = tid + 256 * it;          // 0..1023 (uint4 index)
        uint4 v = *(const uint4*)(Hsrc + (size_t)p * 4);
        int row = p >> 6, c = p & 63;
        uint4* Hrow = (uint4*)&Hp[row * 260];
        Hrow[c] = v;
    }

    int wv = tid >> 6, lane = tid & 63;
    int lrow = lane & 15;
    int g2 = lane >> 4;
    int kgrp = g2 * 8;
    int orow = g2 * 4;

    int t_own = 16 * wv + lrow;
    float4 tq = tb[t_own];
    short8 aq[4];
    make_rot_frags(Cg, ((size_t)b * LL + t0 + t_own) * DQK, tq.x, tq.y, kgrp, aq);
    __syncthreads();

    f32x4 accI[4] = {{0.f,0.f,0.f,0.f},{0.f,0.f,0.f,0.f},
                     {0.f,0.f,0.f,0.f},{0.f,0.f,0.f,0.f}};
    int mt = g2 >> 1;
    int gp0 = 2 * (g2 & 1);
    #pragma unroll
    for (int kk = 0; kk < 4; ++kk) {
        #pragma unroll
        for (int nt = 0; nt < 4; ++nt) {
            int q = mt * 2 + (nt >> 1);
            int row = kk * 4 + q;
            int sb = (nt & 1) * 2;
            const uint2 u0 = *(const uint2*)&Hp[row * 260 + (16 * gp0 + lrow) * 4 + sb];
            const uint2 u1 = *(const uint2*)&Hp[row * 260 + (16 * (gp0 + 1) + lrow) * 4 + sb];
            U8 fr;
            fr.u[0] = u0.x; fr.u[1] = u0.y; fr.u[2] = u1.x; fr.u[3] = u1.y;
            accI[nt] = __builtin_amdgcn_mfma_f32_16x16x32_bf16(
                aq[kk], fr.s, accI[nt], 0, 0, 0);
        }
    }

    #pragma unroll
    for (int rr = 0; rr < 4; ++rr) {
        int t = 16 * wv + orow + rr;
        float g4 = MIMO_RANK * tb[t].w * cdec;
        #pragma unroll
        for (int nt = 0; nt < 4; ++nt) {
            int e = 16 * nt + lrow;
            size_t oidx = ((((size_t)b * LL + t0 + t) * HH) + h) * DV + e;
            out[oidx] = bfbits2f(ytmp[oidx]) + g4 * accI[nt][rr];
        }
    }
}

// ---------------------------------------------------------------------------
extern "C" void kernel_launch(void* const* d_in, const int* in_sizes, int n_in,
                              void* d_out, int out_size, void* d_ws,
                              size_t ws_size, hipStream_t stream) {
    (void)in_sizes; (void)n_in; (void)out_size; (void)ws_size;
    const float* x  = (const float*)d_in[0];
    const float* dt = (const float*)d_in[1];
    const float* A  = (const float*)d_in[2];
    const float* Bg = (const float*)d_in[3];
    const float* Cg = (const float*)d_in[4];
    const float* Dd = (const float*)d_in[5];
    float* out = (float*)d_out;
    float* ws  = (float*)d_ws;

    float4* tbl    = (float4*)ws;                        // B*H*L float4 = 4 MB
    float*  cdecay = ws + (size_t)BB * HH * LL * 4;      // B*N*H = 4096 f32
    ushort* dH     = (ushort*)(cdecay + BB * NN * HH);   // 67 MB bf16
    ushort* ytmp   = dH + (size_t)BB * NN * HH * DQK * DV;  // 33.5 MB bf16

    k_scan_dt<<<BB * HH, 256, 0, stream>>>(dt, A, tbl, cdecay);
    k_intra<<<dim3(NN, HH, BB), 256, 0, stream>>>(x, Bg, Cg, tbl, Dd, ytmp, dH);
    k_scan_chunks<<<(BB * NN * HH * DQK * DV / 4 / NN) / 256, 256, 0, stream>>>(
        (uint2*)dH, cdecay);
    k_inter<<<dim3(NN, HH, BB), 256, 0, stream>>>(Cg, tbl, cdecay, dH, ytmp, out);
}

// Round 15
// 104.328 us; speedup vs baseline: 1.1137x; 1.1137x over previous
//
#include <hip/hip_runtime.h>
#include <hip/hip_bf16.h>

// Problem constants (fixed by setup_inputs)
#define BB 2
#define LL 4096
#define HH 32
#define DV 64
#define DQK 128
#define CC 64            // chunk size
#define NN 64            // number of chunks = LL/CC
#define MIMO_RANK 4.0f

typedef __attribute__((ext_vector_type(8))) short short8;
typedef __attribute__((ext_vector_type(4))) float f32x4;

__device__ __forceinline__ ushort f2bf(float f) {
    __hip_bfloat16 h = __float2bfloat16(f);   // RNE; compiler emits HW cvt
    return *reinterpret_cast<ushort*>(&h);
}
__device__ __forceinline__ float bfbits2f(uint lo16) {
    return __uint_as_float(lo16 << 16);
}
__device__ __forceinline__ uint pkbf2(float lo, float hi) {
    return (uint)f2bf(lo) | ((uint)f2bf(hi) << 16);
}
union U8 { uint u[4]; short8 s; };

// ---- LDS swizzled-offset helpers (element offsets in ushorts) ----
// rk: [64 s][128 d], 16 slots/row, slot ^= (s&7)
__device__ __forceinline__ int rk_off(int s, int d) {
    return s * 128 + (((((d >> 3) & 15) ^ (s & 7)) << 3)) + (d & 7);
}
// uwT: [64 e][64 s], slot ^= (e&7)
__device__ __forceinline__ int uwT_off(int e, int s) {
    return e * 64 + ((((s >> 3) ^ (e & 7)) & 7) << 3) + (s & 7);
}
// SL: [64 t][64 s], slot ^= fSL(t)
__device__ __forceinline__ int fSL(int t) {
    return (((t & 3) << 1) ^ ((t >> 2) & 7)) & 7;
}
__device__ __forceinline__ int SL_off(int t, int s) {
    return t * 64 + ((((s >> 3) ^ fSL(t)) & 7) << 3) + (s & 7);
}

// Build the 4 A-fragments (K=128) of a rotary-transformed row in registers.
__device__ __forceinline__ void make_rot_frags(const float* __restrict__ G,
                                               size_t gb, float cv, float sv,
                                               int kgrp, short8* fr) {
    #pragma unroll
    for (int kk = 0; kk < 4; ++kk) {
        int d0 = kk * 32 + kgrp;
        int dl = d0 & 63;
        bool low = d0 < 64;
        float4 a1 = *(const float4*)(G + gb + dl);
        float4 b1 = *(const float4*)(G + gb + dl + 4);
        float4 a2 = *(const float4*)(G + gb + dl + 64);
        float4 b2 = *(const float4*)(G + gb + dl + 68);
        float v0, v1, v2, v3, v4, v5, v6, v7;
        if (low) {
            v0 = a1.x * cv - a2.x * sv; v1 = a1.y * cv - a2.y * sv;
            v2 = a1.z * cv - a2.z * sv; v3 = a1.w * cv - a2.w * sv;
            v4 = b1.x * cv - b2.x * sv; v5 = b1.y * cv - b2.y * sv;
            v6 = b1.z * cv - b2.z * sv; v7 = b1.w * cv - b2.w * sv;
        } else {
            v0 = a1.x * sv + a2.x * cv; v1 = a1.y * sv + a2.y * cv;
            v2 = a1.z * sv + a2.z * cv; v3 = a1.w * sv + a2.w * cv;
            v4 = b1.x * sv + b2.x * cv; v5 = b1.y * sv + b2.y * cv;
            v6 = b1.z * sv + b2.z * cv; v7 = b1.w * sv + b2.w * cv;
        }
        U8 r;
        r.u[0] = pkbf2(v0, v1); r.u[1] = pkbf2(v2, v3);
        r.u[2] = pkbf2(v4, v5); r.u[3] = pkbf2(v6, v7);
        fr[kk] = r.s;
    }
}

// ---------------------------------------------------------------------------
// K1: prefix sum of dt per (b,h) + precompute table (cos, sin, dt*dw, et)
// per t, plus cdecay per chunk. tbl layout: float4 [b][h][l].
// ---------------------------------------------------------------------------
__global__ __launch_bounds__(256) void k_scan_dt(const float* __restrict__ dt,
                                                 const float* __restrict__ A,
                                                 float4* __restrict__ tbl,
                                                 float* __restrict__ cdecay) {
    int bh = blockIdx.x;
    int b = bh / HH, h = bh % HH;
    int tid = threadIdx.x;
    const int PT = LL / 256;  // 16
    float v[PT];
    float s = 0.f;
    int tbase = tid * PT;
    for (int i = 0; i < PT; ++i) {
        v[i] = dt[(((size_t)b * LL + tbase + i) * HH) + h];
        s += v[i];
    }
    int lane = tid & 63, wv = tid >> 6;
    float ps = s;
    for (int off = 1; off < 64; off <<= 1) {
        float o = __shfl_up(ps, off, 64);
        if (lane >= off) ps += o;
    }
    __shared__ float wsum[4];
    if (lane == 63) wsum[wv] = ps;
    __syncthreads();
    float wadd = 0.f;
    for (int w = 0; w < wv; ++w) wadd += wsum[w];
    float run0 = wadd + ps - s;        // exclusive prefix at tbase
    float run_end = run0 + s;          // inclusive at tbase+15
    float aend  = __shfl(run_end, lane | 3, 64);   // inclusive at chunk end
    float aprev = __shfl(run0, lane & ~3, 64);     // exclusive at chunk start
    float Ah = A[h];
    if ((tid & 3) == 0) {
        int n = tid >> 2;
        cdecay[(b * NN + n) * HH + h] = __expf(Ah * (aend - aprev));
    }
    float4* tb = tbl + ((size_t)(b * HH + h) * LL) + tbase;
    float run = run0;
    for (int i = 0; i < PT; ++i) {
        run += v[i];
        float sv, cv;
        __sincosf(run, &sv, &cv);
        float dw = __expf(Ah * (aend - run));   // decay to chunk end (<=1)
        float et = __expf(Ah * (run - aend));   // inverse factor (>=1)
        tb[i] = make_float4(cv, sv, v[i] * dw, et);
    }
}

// ---------------------------------------------------------------------------
// K2: per-(b,n,h) intra-chunk tile. LDS = 41984 B -> 3 blocks/CU.
// global_load_lds staging (round-13-proven). ytmp (= 4*y_intra + D*x) is now
// stored in the PERMUTED fragment layout via 2x b128 per thread — k_inter's
// accI has the identical fragment mapping and unpacks it directly.
// ---------------------------------------------------------------------------
__global__ __launch_bounds__(256, 3) void k_intra(
    const float* __restrict__ x, const float* __restrict__ Bg,
    const float* __restrict__ Cg, const float4* __restrict__ tbl,
    const float* __restrict__ Dd,
    ushort* __restrict__ ytmp, ushort* __restrict__ dH) {
    int n = blockIdx.x, h = blockIdx.y, b = blockIdx.z;
    int tid = threadIdx.x;
    int t0 = n * CC;

    __shared__ ushort rkS[CC * DQK];     // 16384 B; first 8192 B alias SL later
    __shared__ ushort uwT[DV * CC];      // 8192 B
    __shared__ float4 tblLds[CC];        // 1024 B
    __shared__ float  xraw[CC * DV];     // 16384 B  (row-major [s][e])
    // total 41984 B -> 3 blocks/CU

    int wv = tid >> 6, lane = tid & 63;
    int lrow = lane & 15;
    int g = lane >> 4;
    int kgrp = g * 8;
    int orow = g * 4;

    const float* BgRow = Bg + ((size_t)b * LL + t0) * DQK;  // row s stride 128

    // ============ STEP 0: issue ALL loads (async LDS + reg) ============
    {
        const float4* tbsrc = tbl + ((size_t)(b * HH + h) * LL) + t0 + lane;
        __builtin_amdgcn_global_load_lds((const void*)tbsrc, (void*)tblLds,
                                         16, 0, 0);
    }
    #pragma unroll
    for (int i = 0; i < 4; ++i) {
        int row = 16 * wv + 4 * i + (lane >> 4);
        const float* xsrc = x + ((((size_t)b * LL + t0 + row) * HH) + h) * DV
                            + 4 * (lane & 15);
        __builtin_amdgcn_global_load_lds((const void*)xsrc,
                                         (void*)(xraw + (16 * wv + 4 * i) * DV),
                                         16, 0, 0);
    }
    float4 bg0[2], bg1[2], bg2[2], bg3[2];
    #pragma unroll
    for (int it = 0; it < 2; ++it) {
        int s = (tid >> 3) + 32 * it, oct = tid & 7;
        const float* p = BgRow + s * DQK + 8 * oct;
        bg0[it] = *(const float4*)(p);
        bg1[it] = *(const float4*)(p + 4);
        bg2[it] = *(const float4*)(p + 64);
        bg3[it] = *(const float4*)(p + 68);
    }

    asm volatile("s_waitcnt vmcnt(0)" ::: "memory");
    __builtin_amdgcn_sched_barrier(0);

    // ============ STEP 1: rq frags (Cg loads issue under packing) ============
    int t_own = 16 * wv + lrow;
    float4 tq = tblLds[t_own];
    short8 aq[4];
    make_rot_frags(Cg, ((size_t)b * LL + t0 + t_own) * DQK, tq.x, tq.y, kgrp, aq);

    // ============ STEP 2: rkS pack + write (trig from tblLds) ============
    #pragma unroll
    for (int it = 0; it < 2; ++it) {
        int s = (tid >> 3) + 32 * it, oct = tid & 7;
        float4 tv = tblLds[s];
        float cv = tv.x, sv = tv.y;
        U8 lo, hi;
        lo.u[0] = pkbf2(bg0[it].x * cv - bg2[it].x * sv, bg0[it].y * cv - bg2[it].y * sv);
        lo.u[1] = pkbf2(bg0[it].z * cv - bg2[it].z * sv, bg0[it].w * cv - bg2[it].w * sv);
        lo.u[2] = pkbf2(bg1[it].x * cv - bg3[it].x * sv, bg1[it].y * cv - bg3[it].y * sv);
        lo.u[3] = pkbf2(bg1[it].z * cv - bg3[it].z * sv, bg1[it].w * cv - bg3[it].w * sv);
        hi.u[0] = pkbf2(bg0[it].x * sv + bg2[it].x * cv, bg0[it].y * sv + bg2[it].y * cv);
        hi.u[1] = pkbf2(bg0[it].z * sv + bg2[it].z * cv, bg0[it].w * sv + bg2[it].w * cv);
        hi.u[2] = pkbf2(bg1[it].x * sv + bg3[it].x * cv, bg1[it].y * sv + bg3[it].y * cv);
        hi.u[3] = pkbf2(bg1[it].z * sv + bg3[it].z * cv, bg1[it].w * sv + bg3[it].w * cv);
        *(short8*)&rkS[rk_off(s, 8 * oct)] = lo.s;
        *(short8*)&rkS[rk_off(s, 8 * oct + 64)] = hi.s;
    }

    // ============ STEP 3: uwT from xraw (own-wave rows only) ============
    #pragma unroll
    for (int it = 0; it < 2; ++it) {
        int s0 = 16 * wv + 8 * it;       // within this wave's xraw rows
        int e = lane;
        U8 pk;
        #pragma unroll
        for (int jp = 0; jp < 4; ++jp) {
            int sa = s0 + 2 * jp, sb = sa + 1;
            float xa = xraw[sa * DV + e] * tblLds[sa].z;
            float xb = xraw[sb * DV + e] * tblLds[sb].z;
            pk.u[jp] = pkbf2(xa, xb);
        }
        *(short8*)&uwT[uwT_off(e, s0)] = pk.s;
    }

    __syncthreads();  // BARRIER A: rkS + uwT staged

    // ---- Phase 1: S = rq . rk^T (m = t-rows of wave, n = s, K = 128) ----
    f32x4 accS[4] = {{0.f,0.f,0.f,0.f},{0.f,0.f,0.f,0.f},
                     {0.f,0.f,0.f,0.f},{0.f,0.f,0.f,0.f}};
    #pragma unroll
    for (int kk = 0; kk < 4; ++kk) {
        #pragma unroll
        for (int nt = 0; nt < 4; ++nt) {
            int s = 16 * nt + lrow;
            const short8 bfr = *(const short8*)&rkS[rk_off(s, 32 * kk + kgrp)];
            accS[nt] = __builtin_amdgcn_mfma_f32_16x16x32_bf16(
                aq[kk], bfr, accS[nt], 0, 0, 0);
        }
    }

    // ---- build phase-3 A-frags in registers: aH[kk][mt] = rk[s][d] slices ----
    short8 aH[2][2];
    #pragma unroll
    for (int kk = 0; kk < 2; ++kk) {
        #pragma unroll
        for (int mt = 0; mt < 2; ++mt) {
            int d = 32 * wv + 16 * mt + lrow;
            uint vv[8];
            #pragma unroll
            for (int j = 0; j < 8; ++j)
                vv[j] = rkS[rk_off(32 * kk + kgrp + j, d)];
            U8 pk;
            pk.u[0] = vv[0] | (vv[1] << 16);
            pk.u[1] = vv[2] | (vv[3] << 16);
            pk.u[2] = vv[4] | (vv[5] << 16);
            pk.u[3] = vv[6] | (vv[7] << 16);
            aH[kk][mt] = pk.s;
        }
    }

    __syncthreads();  // BARRIER B: all rkS reads complete -> alias as SL

    // ---- SL = mask(t>=s) * S * et[t], into rkS alias ----
    ushort* SLs = rkS;
    #pragma unroll
    for (int rr = 0; rr < 4; ++rr) {
        int t = 16 * wv + orow + rr;
        float etv = tblLds[t].w;
        #pragma unroll
        for (int nt = 0; nt < 4; ++nt) {
            int s = 16 * nt + lrow;
            float v = (t >= s) ? accS[nt][rr] * etv : 0.f;
            SLs[SL_off(t, s)] = f2bf(v);
        }
    }

    __syncthreads();  // BARRIER C: SL visible

    // ---- Phase 2: y_intra = SL . uwT^T ; ytmp = bf16(4*y + D*x), permuted --
    {
        f32x4 accY[4] = {{0.f,0.f,0.f,0.f},{0.f,0.f,0.f,0.f},
                         {0.f,0.f,0.f,0.f},{0.f,0.f,0.f,0.f}};
        #pragma unroll
        for (int kk = 0; kk < 2; ++kk) {
            const short8 a = *(const short8*)&SLs[SL_off(16 * wv + lrow, 32 * kk + kgrp)];
            #pragma unroll
            for (int nt = 0; nt < 4; ++nt) {
                const short8 bfr = *(const short8*)&uwT[uwT_off(16 * nt + lrow, 32 * kk + kgrp)];
                accY[nt] = __builtin_amdgcn_mfma_f32_16x16x32_bf16(
                    a, bfr, accY[nt], 0, 0, 0);
            }
        }
        float Dh = Dd[h];
        float fin[4][4];
        #pragma unroll
        for (int nt = 0; nt < 4; ++nt) {
            int e = 16 * nt + lrow;
            #pragma unroll
            for (int rr = 0; rr < 4; ++rr) {
                int t = 16 * wv + orow + rr;
                fin[nt][rr] = MIMO_RANK * accY[nt][rr] + Dh * xraw[t * DV + e];
            }
        }
        // permuted store: row = wv*2+q, lane-linear, 16B per thread per q
        ushort* ytp = ytmp + (((size_t)(b * NN + n) * HH) + h) * (CC * DV);
        #pragma unroll
        for (int q = 0; q < 2; ++q) {
            U8 st;
            st.u[0] = pkbf2(fin[2 * q][0], fin[2 * q][1]);
            st.u[1] = pkbf2(fin[2 * q][2], fin[2 * q][3]);
            st.u[2] = pkbf2(fin[2 * q + 1][0], fin[2 * q + 1][1]);
            st.u[3] = pkbf2(fin[2 * q + 1][2], fin[2 * q + 1][3]);
            *(short8*)(ytp + ((size_t)(wv * 2 + q) * 64 + lane) * 8) = st.s;
        }
    }

    // ---- Phase 3: dH = rk^T . uwT^T (m = d, n = e, K = 64), A from regs ----
    {
        f32x4 accH[2][4] = {{{0.f,0.f,0.f,0.f},{0.f,0.f,0.f,0.f},
                             {0.f,0.f,0.f,0.f},{0.f,0.f,0.f,0.f}},
                            {{0.f,0.f,0.f,0.f},{0.f,0.f,0.f,0.f},
                             {0.f,0.f,0.f,0.f},{0.f,0.f,0.f,0.f}}};
        #pragma unroll
        for (int kk = 0; kk < 2; ++kk) {
            #pragma unroll
            for (int mt = 0; mt < 2; ++mt) {
                #pragma unroll
                for (int nt = 0; nt < 4; ++nt) {
                    const short8 bfr = *(const short8*)&uwT[uwT_off(16 * nt + lrow, 32 * kk + kgrp)];
                    accH[mt][nt] = __builtin_amdgcn_mfma_f32_16x16x32_bf16(
                        aH[kk][mt], bfr, accH[mt][nt], 0, 0, 0);
                }
            }
        }
        ushort* dHp = dH + (((size_t)(b * NN + n) * HH) + h) * (DQK * DV);
        #pragma unroll
        for (int q = 0; q < 4; ++q) {
            int mt = q >> 1, np = q & 1;
            U8 st;
            st.u[0] = pkbf2(accH[mt][2 * np][0], accH[mt][2 * np][1]);
            st.u[1] = pkbf2(accH[mt][2 * np][2], accH[mt][2 * np][3]);
            st.u[2] = pkbf2(accH[mt][2 * np + 1][0], accH[mt][2 * np + 1][1]);
            st.u[3] = pkbf2(accH[mt][2 * np + 1][2], accH[mt][2 * np + 1][3]);
            *(short8*)(dHp + ((size_t)(wv * 4 + q) * 64 + lane) * 8) = st.s;
        }
    }
}

// ---------------------------------------------------------------------------
// K3: sequential chunk scan, in place, bf16 pairs, f32 accumulators.
// uint-per-thread (262144 threads) — round-13-proven TLP.
// ---------------------------------------------------------------------------
__global__ __launch_bounds__(256) void k_scan_chunks(
    uint* __restrict__ dH, const float* __restrict__ cdecay) {
    uint f = blockIdx.x * 256 + threadIdx.x;   // 0..262143
    int b = (int)(f >> 17);
    uint r = f & 0x1FFFF;
    int h = (int)((r >> 12) & 31);
    uint base = ((uint)b << 23) | r;
    const float* cd = cdecay + (size_t)b * NN * HH + h;
    float h0 = 0.f, h1 = 0.f;
    for (int n = 0; n < NN; ++n) {
        uint a = base + ((uint)n << 17);
        uint v = dH[a];
        float v0 = bfbits2f(v & 0xFFFF), v1 = bfbits2f(v >> 16);
        dH[a] = pkbf2(h0, h1);       // Hprev for chunk n
        float c = cd[n * HH];
        h0 = c * h0 + v0;
        h1 = c * h1 + v1;
    }
}

// ---------------------------------------------------------------------------
// K4: y_inter + final combine. ytmp read in permuted fragment layout (b128,
// issued early). out = ytmp + 4*et[t]*cdecay[n]*y_inter; single f32 write.
// ---------------------------------------------------------------------------
__global__ __launch_bounds__(256, 4) void k_inter(
    const float* __restrict__ Cg, const float4* __restrict__ tbl,
    const float* __restrict__ cdecay, const ushort* __restrict__ Hprev,
    const ushort* __restrict__ ytmp, float* __restrict__ out) {
    int n = blockIdx.x, h = blockIdx.y, b = blockIdx.z;
    int tid = threadIdx.x;
    int t0 = n * CC;

    __shared__ __align__(16) uint Hp[16 * 260];  // rows 16B-aligned

    const float4* tb = tbl + ((size_t)(b * HH + h) * LL) + t0;
    float cdec = cdecay[(b * NN + n) * HH + h];

    int wv = tid >> 6, lane = tid & 63;
    int lrow = lane & 15;
    int g2 = lane >> 4;
    int kgrp = g2 * 8;
    int orow = g2 * 4;

    // issue ytmp fragment loads early (latency hides under staging + frags)
    const ushort* ytp = ytmp + (((size_t)(b * NN + n) * HH) + h) * (CC * DV);
    U8 y0, y1;
    y0.s = *(const short8*)(ytp + ((size_t)(wv * 2 + 0) * 64 + lane) * 8);
    y1.s = *(const short8*)(ytp + ((size_t)(wv * 2 + 1) * 64 + lane) * 8);

    const uint* Hsrc = (const uint*)(Hprev + (((size_t)(b * NN + n) * HH) + h) * (DQK * DV));
    #pragma unroll
    for (int it = 0; it < 4; ++it) {
        int p = tid + 256 * it;          // 0..1023 (uint4 index)
        uint4 v = *(const uint4*)(Hsrc + (size_t)p * 4);
        int row = p >> 6, c = p & 63;
        uint4* Hrow = (uint4*)&Hp[row * 260];
        Hrow[c] = v;
    }

    int t_own = 16 * wv + lrow;
    float4 tq = tb[t_own];
    short8 aq[4];
    make_rot_frags(Cg, ((size_t)b * LL + t0 + t_own) * DQK, tq.x, tq.y, kgrp, aq);
    __syncthreads();

    f32x4 accI[4] = {{0.f,0.f,0.f,0.f},{0.f,0.f,0.f,0.f},
                     {0.f,0.f,0.f,0.f},{0.f,0.f,0.f,0.f}};
    int mt = g2 >> 1;
    int gp0 = 2 * (g2 & 1);
    #pragma unroll
    for (int kk = 0; kk < 4; ++kk) {
        #pragma unroll
        for (int nt = 0; nt < 4; ++nt) {
            int q = mt * 2 + (nt >> 1);
            int row = kk * 4 + q;
            int sb = (nt & 1) * 2;
            const uint2 u0 = *(const uint2*)&Hp[row * 260 + (16 * gp0 + lrow) * 4 + sb];
            const uint2 u1 = *(const uint2*)&Hp[row * 260 + (16 * (gp0 + 1) + lrow) * 4 + sb];
            U8 fr;
            fr.u[0] = u0.x; fr.u[1] = u0.y; fr.u[2] = u1.x; fr.u[3] = u1.y;
            accI[nt] = __builtin_amdgcn_mfma_f32_16x16x32_bf16(
                aq[kk], fr.s, accI[nt], 0, 0, 0);
        }
    }

    #pragma unroll
    for (int rr = 0; rr < 4; ++rr) {
        int t = 16 * wv + orow + rr;
        float g4 = MIMO_RANK * tb[t].w * cdec;
        #pragma unroll
        for (int nt = 0; nt < 4; ++nt) {
            int e = 16 * nt + lrow;
            uint bits = (nt < 2) ? y0.u[(nt & 1) * 2 + (rr >> 1)]
                                 : y1.u[(nt & 1) * 2 + (rr >> 1)];
            float yv = bfbits2f((rr & 1) ? (bits >> 16) : (bits & 0xFFFF));
            size_t oidx = ((((size_t)b * LL + t0 + t) * HH) + h) * DV + e;
            out[oidx] = yv + g4 * accI[nt][rr];
        }
    }
}

// ---------------------------------------------------------------------------
extern "C" void kernel_launch(void* const* d_in, const int* in_sizes, int n_in,
                              void* d_out, int out_size, void* d_ws,
                              size_t ws_size, hipStream_t stream) {
    (void)in_sizes; (void)n_in; (void)out_size; (void)ws_size;
    const float* x  = (const float*)d_in[0];
    const float* dt = (const float*)d_in[1];
    const float* A  = (const float*)d_in[2];
    const float* Bg = (const float*)d_in[3];
    const float* Cg = (const float*)d_in[4];
    const float* Dd = (const float*)d_in[5];
    float* out = (float*)d_out;
    float* ws  = (float*)d_ws;

    float4* tbl    = (float4*)ws;                        // B*H*L float4 = 4 MB
    float*  cdecay = ws + (size_t)BB * HH * LL * 4;      // B*N*H = 4096 f32
    ushort* dH     = (ushort*)(cdecay + BB * NN * HH);   // 67 MB bf16
    ushort* ytmp   = dH + (size_t)BB * NN * HH * DQK * DV;  // 33.5 MB bf16

    k_scan_dt<<<BB * HH, 256, 0, stream>>>(dt, A, tbl, cdecay);
    k_intra<<<dim3(NN, HH, BB), 256, 0, stream>>>(x, Bg, Cg, tbl, Dd, ytmp, dH);
    k_scan_chunks<<<(BB * HH * DQK * DV / 2) / 256, 256, 0, stream>>>(
        (uint*)dH, cdecay);
    k_inter<<<dim3(NN, HH, BB), 256, 0, stream>>>(Cg, tbl, cdecay, dH, ytmp, out);
}

// Round 16
// 100.283 us; speedup vs baseline: 1.1586x; 1.0403x over previous
//
#include <hip/hip_runtime.h>
#include <hip/hip_bf16.h>

// Problem constants (fixed by setup_inputs)
#define BB 2
#define LL 4096
#define HH 32
#define DV 64
#define DQK 128
#define CC 64            // chunk size
#define NN 64            // number of chunks = LL/CC
#define MIMO_RANK 4.0f

typedef __attribute__((ext_vector_type(8))) short short8;
typedef __attribute__((ext_vector_type(4))) float f32x4;

__device__ __forceinline__ ushort f2bf(float f) {
    __hip_bfloat16 h = __float2bfloat16(f);   // RNE; compiler emits HW cvt
    return *reinterpret_cast<ushort*>(&h);
}
__device__ __forceinline__ float bfbits2f(uint lo16) {
    return __uint_as_float(lo16 << 16);
}
__device__ __forceinline__ uint pkbf2(float lo, float hi) {
    return (uint)f2bf(lo) | ((uint)f2bf(hi) << 16);
}
union U8 { uint u[4]; short8 s; };

// ---- LDS swizzled-offset helpers (element offsets in ushorts) ----
// rk: [64 s][128 d], 16 slots/row, slot ^= (s&7)
__device__ __forceinline__ int rk_off(int s, int d) {
    return s * 128 + (((((d >> 3) & 15) ^ (s & 7)) << 3)) + (d & 7);
}
// uwT: [64 e][64 s], slot ^= (e&7)
__device__ __forceinline__ int uwT_off(int e, int s) {
    return e * 64 + ((((s >> 3) ^ (e & 7)) & 7) << 3) + (s & 7);
}
// SL: [64 t][64 s], slot ^= fSL(t)
__device__ __forceinline__ int fSL(int t) {
    return (((t & 3) << 1) ^ ((t >> 2) & 7)) & 7;
}
__device__ __forceinline__ int SL_off(int t, int s) {
    return t * 64 + ((((s >> 3) ^ fSL(t)) & 7) << 3) + (s & 7);
}

// Build the 4 A-fragments (K=128) of a rotary-transformed row in registers.
__device__ __forceinline__ void make_rot_frags(const float* __restrict__ G,
                                               size_t gb, float cv, float sv,
                                               int kgrp, short8* fr) {
    #pragma unroll
    for (int kk = 0; kk < 4; ++kk) {
        int d0 = kk * 32 + kgrp;
        int dl = d0 & 63;
        bool low = d0 < 64;
        float4 a1 = *(const float4*)(G + gb + dl);
        float4 b1 = *(const float4*)(G + gb + dl + 4);
        float4 a2 = *(const float4*)(G + gb + dl + 64);
        float4 b2 = *(const float4*)(G + gb + dl + 68);
        float v0, v1, v2, v3, v4, v5, v6, v7;
        if (low) {
            v0 = a1.x * cv - a2.x * sv; v1 = a1.y * cv - a2.y * sv;
            v2 = a1.z * cv - a2.z * sv; v3 = a1.w * cv - a2.w * sv;
            v4 = b1.x * cv - b2.x * sv; v5 = b1.y * cv - b2.y * sv;
            v6 = b1.z * cv - b2.z * sv; v7 = b1.w * cv - b2.w * sv;
        } else {
            v0 = a1.x * sv + a2.x * cv; v1 = a1.y * sv + a2.y * cv;
            v2 = a1.z * sv + a2.z * cv; v3 = a1.w * sv + a2.w * cv;
            v4 = b1.x * sv + b2.x * cv; v5 = b1.y * sv + b2.y * cv;
            v6 = b1.z * sv + b2.z * cv; v7 = b1.w * sv + b2.w * cv;
        }
        U8 r;
        r.u[0] = pkbf2(v0, v1); r.u[1] = pkbf2(v2, v3);
        r.u[2] = pkbf2(v4, v5); r.u[3] = pkbf2(v6, v7);
        fr[kk] = r.s;
    }
}

// ---------------------------------------------------------------------------
// K1: prefix sum of dt per (b,h) + precompute table (cos, sin, dt*dw, et)
// per t, plus cdecay per chunk. tbl layout: float4 [b][h][l].
// ---------------------------------------------------------------------------
__global__ __launch_bounds__(256) void k_scan_dt(const float* __restrict__ dt,
                                                 const float* __restrict__ A,
                                                 float4* __restrict__ tbl,
                                                 float* __restrict__ cdecay) {
    int bh = blockIdx.x;
    int b = bh / HH, h = bh % HH;
    int tid = threadIdx.x;
    const int PT = LL / 256;  // 16
    float v[PT];
    float s = 0.f;
    int tbase = tid * PT;
    for (int i = 0; i < PT; ++i) {
        v[i] = dt[(((size_t)b * LL + tbase + i) * HH) + h];
        s += v[i];
    }
    int lane = tid & 63, wv = tid >> 6;
    float ps = s;
    for (int off = 1; off < 64; off <<= 1) {
        float o = __shfl_up(ps, off, 64);
        if (lane >= off) ps += o;
    }
    __shared__ float wsum[4];
    if (lane == 63) wsum[wv] = ps;
    __syncthreads();
    float wadd = 0.f;
    for (int w = 0; w < wv; ++w) wadd += wsum[w];
    float run0 = wadd + ps - s;        // exclusive prefix at tbase
    float run_end = run0 + s;          // inclusive at tbase+15
    float aend  = __shfl(run_end, lane | 3, 64);   // inclusive at chunk end
    float aprev = __shfl(run0, lane & ~3, 64);     // exclusive at chunk start
    float Ah = A[h];
    if ((tid & 3) == 0) {
        int n = tid >> 2;
        cdecay[(b * NN + n) * HH + h] = __expf(Ah * (aend - aprev));
    }
    float4* tb = tbl + ((size_t)(b * HH + h) * LL) + tbase;
    float run = run0;
    for (int i = 0; i < PT; ++i) {
        run += v[i];
        float sv, cv;
        __sincosf(run, &sv, &cv);
        float dw = __expf(Ah * (aend - run));   // decay to chunk end (<=1)
        float et = __expf(Ah * (run - aend));   // inverse factor (>=1)
        tb[i] = make_float4(cv, sv, v[i] * dw, et);
    }
}

// ---------------------------------------------------------------------------
// K2: per-(b,n,h) intra-chunk tile. LDS = 50176 B -> 3 blocks/CU; 2 barriers.
// Staggered waits: Bg/tbl reg loads issued FIRST, global_load_lds LAST, so
// the rkS pack auto-waits only on its reg loads (lds loads stay in flight
// under ~150 VALU ops); manual vmcnt(0) just before the uwT pack. SL has its
// own buffer (no rkS alias) -> barrier B eliminated.
// ---------------------------------------------------------------------------
__global__ __launch_bounds__(256, 3) void k_intra(
    const float* __restrict__ x, const float* __restrict__ Bg,
    const float* __restrict__ Cg, const float4* __restrict__ tbl,
    const float* __restrict__ Dd,
    ushort* __restrict__ ytmp, ushort* __restrict__ dH) {
    int n = blockIdx.x, h = blockIdx.y, b = blockIdx.z;
    int tid = threadIdx.x;
    int t0 = n * CC;

    __shared__ ushort rkS[CC * DQK];     // 16384 B
    __shared__ ushort SLb[CC * CC];      // 8192 B (dedicated SL)
    __shared__ ushort uwT[DV * CC];      // 8192 B
    __shared__ float4 tblLds[CC];        // 1024 B
    __shared__ float  xraw[CC * DV];     // 16384 B  (row-major [s][e])
    // total 50176 B -> 3 blocks/CU

    int wv = tid >> 6, lane = tid & 63;
    int lrow = lane & 15;
    int g = lane >> 4;
    int kgrp = g * 8;
    int orow = g * 4;

    const float* BgRow = Bg + ((size_t)b * LL + t0) * DQK;  // row s stride 128
    const float4* tbg = tbl + ((size_t)(b * HH + h) * LL) + t0;

    // ===== STEP 0a: issue reg loads FIRST (Bg + per-chunk trig) =====
    float4 bg0[2], bg1[2], bg2[2], bg3[2], tvS[2];
    #pragma unroll
    for (int it = 0; it < 2; ++it) {
        int s = (tid >> 3) + 32 * it, oct = tid & 7;
        const float* p = BgRow + s * DQK + 8 * oct;
        bg0[it] = *(const float4*)(p);
        bg1[it] = *(const float4*)(p + 4);
        bg2[it] = *(const float4*)(p + 64);
        bg3[it] = *(const float4*)(p + 68);
        tvS[it] = tbg[s];                  // L2-hot direct read
    }
    int t_own = 16 * wv + lrow;
    float4 tq = tbg[t_own];                // L2-hot direct read

    // ===== STEP 0b: issue global_load_lds LAST (stay in flight) =====
    {
        const float4* tbsrc = tbg + lane;
        __builtin_amdgcn_global_load_lds((const void*)tbsrc, (void*)tblLds,
                                         16, 0, 0);
    }
    #pragma unroll
    for (int i = 0; i < 4; ++i) {
        int row = 16 * wv + 4 * i + (lane >> 4);
        const float* xsrc = x + ((((size_t)b * LL + t0 + row) * HH) + h) * DV
                            + 4 * (lane & 15);
        __builtin_amdgcn_global_load_lds((const void*)xsrc,
                                         (void*)(xraw + (16 * wv + 4 * i) * DV),
                                         16, 0, 0);
    }
    __builtin_amdgcn_sched_barrier(0);

    // ===== STEP 1: rkS pack (waits only on reg loads; lds in flight) =====
    #pragma unroll
    for (int it = 0; it < 2; ++it) {
        int s = (tid >> 3) + 32 * it, oct = tid & 7;
        float cv = tvS[it].x, sv = tvS[it].y;
        U8 lo, hi;
        lo.u[0] = pkbf2(bg0[it].x * cv - bg2[it].x * sv, bg0[it].y * cv - bg2[it].y * sv);
        lo.u[1] = pkbf2(bg0[it].z * cv - bg2[it].z * sv, bg0[it].w * cv - bg2[it].w * sv);
        lo.u[2] = pkbf2(bg1[it].x * cv - bg3[it].x * sv, bg1[it].y * cv - bg3[it].y * sv);
        lo.u[3] = pkbf2(bg1[it].z * cv - bg3[it].z * sv, bg1[it].w * cv - bg3[it].w * sv);
        hi.u[0] = pkbf2(bg0[it].x * sv + bg2[it].x * cv, bg0[it].y * sv + bg2[it].y * cv);
        hi.u[1] = pkbf2(bg0[it].z * sv + bg2[it].z * cv, bg0[it].w * sv + bg2[it].w * cv);
        hi.u[2] = pkbf2(bg1[it].x * sv + bg3[it].x * cv, bg1[it].y * sv + bg3[it].y * cv);
        hi.u[3] = pkbf2(bg1[it].z * sv + bg3[it].z * cv, bg1[it].w * sv + bg3[it].w * cv);
        *(short8*)&rkS[rk_off(s, 8 * oct)] = lo.s;
        *(short8*)&rkS[rk_off(s, 8 * oct + 64)] = hi.s;
    }

    // ===== STEP 2: rq frags (Cg loads + pack; drains remaining vmcnt) =====
    short8 aq[4];
    make_rot_frags(Cg, ((size_t)b * LL + t0 + t_own) * DQK, tq.x, tq.y, kgrp, aq);

    // ===== STEP 3: wait for gload_lds, then uwT pack from xraw =====
    asm volatile("s_waitcnt vmcnt(0)" ::: "memory");
    __builtin_amdgcn_sched_barrier(0);
    #pragma unroll
    for (int it = 0; it < 2; ++it) {
        int s0 = 16 * wv + 8 * it;       // within this wave's xraw rows
        int e = lane;
        U8 pk;
        #pragma unroll
        for (int jp = 0; jp < 4; ++jp) {
            int sa = s0 + 2 * jp, sb = sa + 1;
            float xa = xraw[sa * DV + e] * tblLds[sa].z;
            float xb = xraw[sb * DV + e] * tblLds[sb].z;
            pk.u[jp] = pkbf2(xa, xb);
        }
        *(short8*)&uwT[uwT_off(e, s0)] = pk.s;
    }

    __syncthreads();  // BARRIER A: rkS + uwT staged

    // ---- Phase 1: S = rq . rk^T (m = t-rows of wave, n = s, K = 128) ----
    f32x4 accS[4] = {{0.f,0.f,0.f,0.f},{0.f,0.f,0.f,0.f},
                     {0.f,0.f,0.f,0.f},{0.f,0.f,0.f,0.f}};
    #pragma unroll
    for (int kk = 0; kk < 4; ++kk) {
        #pragma unroll
        for (int nt = 0; nt < 4; ++nt) {
            int s = 16 * nt + lrow;
            const short8 bfr = *(const short8*)&rkS[rk_off(s, 32 * kk + kgrp)];
            accS[nt] = __builtin_amdgcn_mfma_f32_16x16x32_bf16(
                aq[kk], bfr, accS[nt], 0, 0, 0);
        }
    }

    // ---- build phase-3 A-frags in registers (rkS is never overwritten) ----
    short8 aH[2][2];
    #pragma unroll
    for (int kk = 0; kk < 2; ++kk) {
        #pragma unroll
        for (int mt = 0; mt < 2; ++mt) {
            int d = 32 * wv + 16 * mt + lrow;
            uint vv[8];
            #pragma unroll
            for (int j = 0; j < 8; ++j)
                vv[j] = rkS[rk_off(32 * kk + kgrp + j, d)];
            U8 pk;
            pk.u[0] = vv[0] | (vv[1] << 16);
            pk.u[1] = vv[2] | (vv[3] << 16);
            pk.u[2] = vv[4] | (vv[5] << 16);
            pk.u[3] = vv[6] | (vv[7] << 16);
            aH[kk][mt] = pk.s;
        }
    }

    // ---- SL = mask(t>=s) * S * et[t], into dedicated SLb ----
    #pragma unroll
    for (int rr = 0; rr < 4; ++rr) {
        int t = 16 * wv + orow + rr;
        float etv = tblLds[t].w;
        #pragma unroll
        for (int nt = 0; nt < 4; ++nt) {
            int s = 16 * nt + lrow;
            float v = (t >= s) ? accS[nt][rr] * etv : 0.f;
            SLb[SL_off(t, s)] = f2bf(v);
        }
    }

    __syncthreads();  // BARRIER C: SL visible

    // ---- Phase 2: y_intra = SL . uwT^T ; ytmp = bf16(4*y + D*x), permuted --
    {
        f32x4 accY[4] = {{0.f,0.f,0.f,0.f},{0.f,0.f,0.f,0.f},
                         {0.f,0.f,0.f,0.f},{0.f,0.f,0.f,0.f}};
        #pragma unroll
        for (int kk = 0; kk < 2; ++kk) {
            const short8 a = *(const short8*)&SLb[SL_off(16 * wv + lrow, 32 * kk + kgrp)];
            #pragma unroll
            for (int nt = 0; nt < 4; ++nt) {
                const short8 bfr = *(const short8*)&uwT[uwT_off(16 * nt + lrow, 32 * kk + kgrp)];
                accY[nt] = __builtin_amdgcn_mfma_f32_16x16x32_bf16(
                    a, bfr, accY[nt], 0, 0, 0);
            }
        }
        float Dh = Dd[h];
        float fin[4][4];
        #pragma unroll
        for (int nt = 0; nt < 4; ++nt) {
            int e = 16 * nt + lrow;
            #pragma unroll
            for (int rr = 0; rr < 4; ++rr) {
                int t = 16 * wv + orow + rr;
                fin[nt][rr] = MIMO_RANK * accY[nt][rr] + Dh * xraw[t * DV + e];
            }
        }
        ushort* ytp = ytmp + (((size_t)(b * NN + n) * HH) + h) * (CC * DV);
        #pragma unroll
        for (int q = 0; q < 2; ++q) {
            U8 st;
            st.u[0] = pkbf2(fin[2 * q][0], fin[2 * q][1]);
            st.u[1] = pkbf2(fin[2 * q][2], fin[2 * q][3]);
            st.u[2] = pkbf2(fin[2 * q + 1][0], fin[2 * q + 1][1]);
            st.u[3] = pkbf2(fin[2 * q + 1][2], fin[2 * q + 1][3]);
            *(short8*)(ytp + ((size_t)(wv * 2 + q) * 64 + lane) * 8) = st.s;
        }
    }

    // ---- Phase 3: dH = rk^T . uwT^T (m = d, n = e, K = 64), A from regs ----
    {
        f32x4 accH[2][4] = {{{0.f,0.f,0.f,0.f},{0.f,0.f,0.f,0.f},
                             {0.f,0.f,0.f,0.f},{0.f,0.f,0.f,0.f}},
                            {{0.f,0.f,0.f,0.f},{0.f,0.f,0.f,0.f},
                             {0.f,0.f,0.f,0.f},{0.f,0.f,0.f,0.f}}};
        #pragma unroll
        for (int kk = 0; kk < 2; ++kk) {
            #pragma unroll
            for (int mt = 0; mt < 2; ++mt) {
                #pragma unroll
                for (int nt = 0; nt < 4; ++nt) {
                    const short8 bfr = *(const short8*)&uwT[uwT_off(16 * nt + lrow, 32 * kk + kgrp)];
                    accH[mt][nt] = __builtin_amdgcn_mfma_f32_16x16x32_bf16(
                        aH[kk][mt], bfr, accH[mt][nt], 0, 0, 0);
                }
            }
        }
        ushort* dHp = dH + (((size_t)(b * NN + n) * HH) + h) * (DQK * DV);
        #pragma unroll
        for (int q = 0; q < 4; ++q) {
            int mt = q >> 1, np = q & 1;
            U8 st;
            st.u[0] = pkbf2(accH[mt][2 * np][0], accH[mt][2 * np][1]);
            st.u[1] = pkbf2(accH[mt][2 * np][2], accH[mt][2 * np][3]);
            st.u[2] = pkbf2(accH[mt][2 * np + 1][0], accH[mt][2 * np + 1][1]);
            st.u[3] = pkbf2(accH[mt][2 * np + 1][2], accH[mt][2 * np + 1][3]);
            *(short8*)(dHp + ((size_t)(wv * 4 + q) * 64 + lane) * 8) = st.s;
        }
    }
}

// ---------------------------------------------------------------------------
// K3: sequential chunk scan, in place, bf16 pairs, f32 accumulators.
// uint-per-thread (262144 threads) — proven TLP.
// ---------------------------------------------------------------------------
__global__ __launch_bounds__(256) void k_scan_chunks(
    uint* __restrict__ dH, const float* __restrict__ cdecay) {
    uint f = blockIdx.x * 256 + threadIdx.x;   // 0..262143
    int b = (int)(f >> 17);
    uint r = f & 0x1FFFF;
    int h = (int)((r >> 12) & 31);
    uint base = ((uint)b << 23) | r;
    const float* cd = cdecay + (size_t)b * NN * HH + h;
    float h0 = 0.f, h1 = 0.f;
    for (int n = 0; n < NN; ++n) {
        uint a = base + ((uint)n << 17);
        uint v = dH[a];
        float v0 = bfbits2f(v & 0xFFFF), v1 = bfbits2f(v >> 16);
        dH[a] = pkbf2(h0, h1);       // Hprev for chunk n
        float c = cd[n * HH];
        h0 = c * h0 + v0;
        h1 = c * h1 + v1;
    }
}

// ---------------------------------------------------------------------------
// K4: y_inter + final combine. ytmp read in permuted fragment layout (b128,
// issued early). out = ytmp + 4*et[t]*cdecay[n]*y_inter; single f32 write.
// ---------------------------------------------------------------------------
__global__ __launch_bounds__(256, 4) void k_inter(
    const float* __restrict__ Cg, const float4* __restrict__ tbl,
    const float* __restrict__ cdecay, const ushort* __restrict__ Hprev,
    const ushort* __restrict__ ytmp, float* __restrict__ out) {
    int n = blockIdx.x, h = blockIdx.y, b = blockIdx.z;
    int tid = threadIdx.x;
    int t0 = n * CC;

    __shared__ __align__(16) uint Hp[16 * 260];  // rows 16B-aligned

    const float4* tb = tbl + ((size_t)(b * HH + h) * LL) + t0;
    float cdec = cdecay[(b * NN + n) * HH + h];

    int wv = tid >> 6, lane = tid & 63;
    int lrow = lane & 15;
    int g2 = lane >> 4;
    int kgrp = g2 * 8;
    int orow = g2 * 4;

    // issue ytmp fragment loads early (latency hides under staging + frags)
    const ushort* ytp = ytmp + (((size_t)(b * NN + n) * HH) + h) * (CC * DV);
    U8 y0, y1;
    y0.s = *(const short8*)(ytp + ((size_t)(wv * 2 + 0) * 64 + lane) * 8);
    y1.s = *(const short8*)(ytp + ((size_t)(wv * 2 + 1) * 64 + lane) * 8);

    const uint* Hsrc = (const uint*)(Hprev + (((size_t)(b * NN + n) * HH) + h) * (DQK * DV));
    #pragma unroll
    for (int it = 0; it < 4; ++it) {
        int p = tid + 256 * it;          // 0..1023 (uint4 index)
        uint4 v = *(const uint4*)(Hsrc + (size_t)p * 4);
        int row = p >> 6, c = p & 63;
        uint4* Hrow = (uint4*)&Hp[row * 260];
        Hrow[c] = v;
    }

    int t_own = 16 * wv + lrow;
    float4 tq = tb[t_own];
    short8 aq[4];
    make_rot_frags(Cg, ((size_t)b * LL + t0 + t_own) * DQK, tq.x, tq.y, kgrp, aq);
    __syncthreads();

    f32x4 accI[4] = {{0.f,0.f,0.f,0.f},{0.f,0.f,0.f,0.f},
                     {0.f,0.f,0.f,0.f},{0.f,0.f,0.f,0.f}};
    int mt = g2 >> 1;
    int gp0 = 2 * (g2 & 1);
    #pragma unroll
    for (int kk = 0; kk < 4; ++kk) {
        #pragma unroll
        for (int nt = 0; nt < 4; ++nt) {
            int q = mt * 2 + (nt >> 1);
            int row = kk * 4 + q;
            int sb = (nt & 1) * 2;
            const uint2 u0 = *(const uint2*)&Hp[row * 260 + (16 * gp0 + lrow) * 4 + sb];
            const uint2 u1 = *(const uint2*)&Hp[row * 260 + (16 * (gp0 + 1) + lrow) * 4 + sb];
            U8 fr;
            fr.u[0] = u0.x; fr.u[1] = u0.y; fr.u[2] = u1.x; fr.u[3] = u1.y;
            accI[nt] = __builtin_amdgcn_mfma_f32_16x16x32_bf16(
                aq[kk], fr.s, accI[nt], 0, 0, 0);
        }
    }

    #pragma unroll
    for (int rr = 0; rr < 4; ++rr) {
        int t = 16 * wv + orow + rr;
        float g4 = MIMO_RANK * tb[t].w * cdec;
        #pragma unroll
        for (int nt = 0; nt < 4; ++nt) {
            int e = 16 * nt + lrow;
            uint bits = (nt < 2) ? y0.u[(nt & 1) * 2 + (rr >> 1)]
                                 : y1.u[(nt & 1) * 2 + (rr >> 1)];
            float yv = bfbits2f((rr & 1) ? (bits >> 16) : (bits & 0xFFFF));
            size_t oidx = ((((size_t)b * LL + t0 + t) * HH) + h) * DV + e;
            out[oidx] = yv + g4 * accI[nt][rr];
        }
    }
}

// ---------------------------------------------------------------------------
extern "C" void kernel_launch(void* const* d_in, const int* in_sizes, int n_in,
                              void* d_out, int out_size, void* d_ws,
                              size_t ws_size, hipStream_t stream) {
    (void)in_sizes; (void)n_in; (void)out_size; (void)ws_size;
    const float* x  = (const float*)d_in[0];
    const float* dt = (const float*)d_in[1];
    const float* A  = (const float*)d_in[2];
    const float* Bg = (const float*)d_in[3];
    const float* Cg = (const float*)d_in[4];
    const float* Dd = (const float*)d_in[5];
    float* out = (float*)d_out;
    float* ws  = (float*)d_ws;

    float4* tbl    = (float4*)ws;                        // B*H*L float4 = 4 MB
    float*  cdecay = ws + (size_t)BB * HH * LL * 4;      // B*N*H = 4096 f32
    ushort* dH     = (ushort*)(cdecay + BB * NN * HH);   // 67 MB bf16
    ushort* ytmp   = dH + (size_t)BB * NN * HH * DQK * DV;  // 33.5 MB bf16

    k_scan_dt<<<BB * HH, 256, 0, stream>>>(dt, A, tbl, cdecay);
    k_intra<<<dim3(NN, HH, BB), 256, 0, stream>>>(x, Bg, Cg, tbl, Dd, ytmp, dH);
    k_scan_chunks<<<(BB * HH * DQK * DV / 2) / 256, 256, 0, stream>>>(
        (uint*)dH, cdecay);
    k_inter<<<dim3(NN, HH, BB), 256, 0, stream>>>(Cg, tbl, cdecay, dH, ytmp, out);
}